// Round 1
// baseline (2082.769 us; speedup 1.0000x reference)
//
#include <hip/hip_runtime.h>
#include <math.h>

// ---------------------------------------------------------------------------
// BiNet forward: 7 x [conv1d(binarized W) -> maxpool -> BN(batch stats) -> sign]
// then FC with binarized weights. Batch N=2048, input [N,1,3600] fp32.
//
// Layer table (Cin, Lin, O, K, stride, pad, Lconv, pk, ps, Lp):
//  1: (1,3600, 8,16,2,7,1800, 8,4,449)
//  2: (8, 449,12,12,2,5, 224, 4,2,111)
//  3: (12,111,32, 9,1,4, 111, 5,2, 54)
//  4: (32, 54,64, 7,1,3,  54, 4,2, 26)
//  5: (64, 26,64, 5,1,2,  26, 2,2, 13)
//  6: (64, 13,64, 3,1,1,  13, 2,2,  6)
//  7: (64,  6,72, 3,1,1,   6, 2,2,  3)
// FC: [5,216] over flattened [72*3].
// ---------------------------------------------------------------------------

#define NBATCH 2048

__device__ __forceinline__ float signf(float v) {
    return (v > 0.f) ? 1.f : ((v < 0.f) ? -1.f : 0.f);
}

// ---- per-output-channel weight scale: mean |w| over (Cin*K) -----------------
__global__ void wscale_kernel(const float* __restrict__ w, float* __restrict__ out, int per) {
    int o = blockIdx.x;
    const float* wo = w + (size_t)o * per;
    float s = 0.f;
    for (int i = threadIdx.x; i < per; i += 64) s += fabsf(wo[i]);
    #pragma unroll
    for (int off = 32; off > 0; off >>= 1) s += __shfl_down(s, off);
    if (threadIdx.x == 0) out[o] = s / (float)per;
}

// ---- fold BN batch stats into affine (a,b): y = a*x + b ---------------------
__global__ void bnparam_kernel(const double* __restrict__ stats,
                               const float* __restrict__ gamma,
                               const float* __restrict__ beta,
                               float* __restrict__ ab, int O, double cntInv) {
    int o = threadIdx.x;
    if (o < O) {
        double mean = stats[o] * cntInv;
        double var  = stats[O + o] * cntInv - mean * mean;
        double inv  = 1.0 / sqrt(var + 1e-5);
        double a    = (double)gamma[o] * inv;
        ab[o]     = (float)a;
        ab[O + o] = (float)((double)beta[o] - mean * a);
    }
}

// ---- fused conv + maxpool + BN-stats block ---------------------------------
// grid = (N, O/OG); block = 256. Input row + weight signs + conv intermediates
// all staged in LDS. If `ab` != null, input values are sign(a*x+b) (previous
// layer's BN+bin_act applied on load).
template <int CIN, int LIN, int O, int OG, int K, int STRIDE, int PAD,
          int LCONV, int PK, int PS, int LP>
__global__ __launch_bounds__(256) void convblock(
    const float* __restrict__ x, const float* __restrict__ w,
    const float* __restrict__ wsc, const float* __restrict__ ab,
    float* __restrict__ out, double* __restrict__ stats)
{
    extern __shared__ float lds[];
    constexpr int XS = CIN * LIN;
    constexpr int WSZ = OG * CIN * K;
    constexpr int CV = OG * LCONV;
    float* xs = lds;            // input row (raw or signed)
    float* wg = xs + XS;        // weight signs for this channel group
    float* cv = wg + WSZ;       // conv outputs
    float* pl = cv + CV;        // pooled outputs (for stats)

    const int n  = blockIdx.x;
    const int o0 = blockIdx.y * OG;
    const int tid = threadIdx.x;
    const int T = 256;

    const float* xn = x + (size_t)n * XS;
    if (ab != nullptr) {
        for (int i = tid; i < XS; i += T) {
            int c = i / LIN;
            float v = fmaf(ab[c], xn[i], ab[CIN + c]);
            xs[i] = signf(v);
        }
    } else {
        for (int i = tid; i < XS; i += T) xs[i] = xn[i];
    }
    for (int i = tid; i < WSZ; i += T)
        wg[i] = signf(w[(size_t)o0 * CIN * K + i]);
    __syncthreads();

    // conv phase
    for (int idx = tid; idx < CV; idx += T) {
        int oo = idx / LCONV, lc = idx % LCONV;
        int base = lc * STRIDE - PAD;
        const float* wo = wg + oo * CIN * K;
        float s = 0.f;
        if (base >= 0 && base + K <= LIN) {
            #pragma unroll
            for (int c = 0; c < CIN; ++c) {
                #pragma unroll
                for (int k = 0; k < K; ++k)
                    s = fmaf(xs[c * LIN + base + k], wo[c * K + k], s);
            }
        } else {
            #pragma unroll
            for (int c = 0; c < CIN; ++c) {
                #pragma unroll
                for (int k = 0; k < K; ++k) {
                    int p = base + k;
                    if (p >= 0 && p < LIN)
                        s = fmaf(xs[c * LIN + p], wo[c * K + k], s);
                }
            }
        }
        cv[idx] = s * wsc[o0 + oo];
    }
    __syncthreads();

    // pool phase + write out
    float* on = out + ((size_t)n * O + o0) * LP;
    for (int idx = tid; idx < OG * LP; idx += T) {
        int oo = idx / LP, lp = idx % LP;
        const float* cvo = cv + oo * LCONV + lp * PS;
        float m = cvo[0];
        #pragma unroll
        for (int j = 1; j < PK; ++j) m = fmaxf(m, cvo[j]);
        pl[idx] = m;
        on[(size_t)oo * LP + lp] = m;
    }
    __syncthreads();

    // per-channel stats (double atomics for BN-threshold accuracy)
    if (tid < OG) {
        double s = 0.0, s2 = 0.0;
        const float* po = pl + tid * LP;
        for (int l = 0; l < LP; ++l) { double v = po[l]; s += v; s2 += v * v; }
        atomicAdd(&stats[o0 + tid], s);
        atomicAdd(&stats[O + o0 + tid], s2);
    }
}

// ---- final FC over flattened [72*3] -----------------------------------------
__global__ __launch_bounds__(256) void fc_kernel(
    const float* __restrict__ p7, const float* __restrict__ ab,
    const float* __restrict__ wfc, const float* __restrict__ wsc,
    float* __restrict__ out)
{
    __shared__ float act[216];
    int n = blockIdx.x, tid = threadIdx.x;
    for (int i = tid; i < 216; i += 256) {
        int c = i / 3;
        act[i] = signf(fmaf(ab[c], p7[(size_t)n * 216 + i], ab[72 + c]));
    }
    __syncthreads();
    if (tid < 5) {
        const float* wr = wfc + tid * 216;
        float s = 0.f;
        #pragma unroll 8
        for (int i = 0; i < 216; ++i) s += act[i] * signf(wr[i]);
        out[(size_t)n * 5 + tid] = s * wsc[tid];
    }
}

extern "C" void kernel_launch(void* const* d_in, const int* in_sizes, int n_in,
                              void* d_out, int out_size, void* d_ws, size_t ws_size,
                              hipStream_t stream) {
    const float* x = (const float*)d_in[0];
    const float* W[7]; const float* Gp[7]; const float* Bp[7];
    for (int i = 0; i < 7; ++i) {
        W[i]  = (const float*)d_in[1 + 3 * i];
        Gp[i] = (const float*)d_in[2 + 3 * i];
        Bp[i] = (const float*)d_in[3 + 3 * i];
    }
    const float* WFC = (const float*)d_in[22];
    float* outp = (float*)d_out;

    // workspace layout
    char* ws = (char*)d_ws;
    double* stats = (double*)ws;                    // 632 doubles (per-layer 2*O)
    float*  abbuf = (float*)(ws + 5120);            // 632 floats
    float*  wsc   = (float*)(ws + 7680);            // 321 floats
    float*  bufA  = (float*)(ws + 9216);            // 7,356,416 floats (p1/p3/p5/p7)
    float*  bufB  = bufA + 7356416;                 // 3,407,872 floats (p2/p4/p6)

    hipMemsetAsync(stats, 0, 632 * sizeof(double), stream);

    // weight scales
    wscale_kernel<<<8,  64, 0, stream>>>(W[0], wsc + 0,   16);
    wscale_kernel<<<12, 64, 0, stream>>>(W[1], wsc + 8,   96);
    wscale_kernel<<<32, 64, 0, stream>>>(W[2], wsc + 20, 108);
    wscale_kernel<<<64, 64, 0, stream>>>(W[3], wsc + 52, 224);
    wscale_kernel<<<64, 64, 0, stream>>>(W[4], wsc + 116,320);
    wscale_kernel<<<64, 64, 0, stream>>>(W[5], wsc + 180,192);
    wscale_kernel<<<72, 64, 0, stream>>>(W[6], wsc + 244,192);
    wscale_kernel<<<5,  64, 0, stream>>>(WFC,  wsc + 316,216);

    // layer 1
    convblock<1,3600,8,4,16,2,7,1800,8,4,449>
        <<<dim3(NBATCH,2), 256, 50640, stream>>>(x, W[0], wsc + 0, nullptr, bufA, stats + 0);
    bnparam_kernel<<<1,128,0,stream>>>(stats + 0, Gp[0], Bp[0], abbuf + 0, 8, 1.0/919552.0);
    // layer 2
    convblock<8,449,12,12,12,2,5,224,4,2,111>
        <<<dim3(NBATCH,1), 256, 35056, stream>>>(bufA, W[1], wsc + 8, abbuf + 0, bufB, stats + 16);
    bnparam_kernel<<<1,128,0,stream>>>(stats + 16, Gp[1], Bp[1], abbuf + 16, 12, 1.0/227328.0);
    // layer 3
    convblock<12,111,32,32,9,1,4,111,5,2,54>
        <<<dim3(NBATCH,1), 256, 40272, stream>>>(bufB, W[2], wsc + 20, abbuf + 16, bufA, stats + 40);
    bnparam_kernel<<<1,128,0,stream>>>(stats + 40, Gp[2], Bp[2], abbuf + 40, 32, 1.0/110592.0);
    // layer 4
    convblock<32,54,64,32,7,1,3,54,4,2,26>
        <<<dim3(NBATCH,2), 256, 45824, stream>>>(bufA, W[3], wsc + 52, abbuf + 40, bufB, stats + 104);
    bnparam_kernel<<<1,128,0,stream>>>(stats + 104, Gp[3], Bp[3], abbuf + 104, 64, 1.0/53248.0);
    // layer 5
    convblock<64,26,64,32,5,1,2,26,2,2,13>
        <<<dim3(NBATCH,2), 256, 52608, stream>>>(bufB, W[4], wsc + 116, abbuf + 104, bufA, stats + 232);
    bnparam_kernel<<<1,128,0,stream>>>(stats + 232, Gp[4], Bp[4], abbuf + 232, 64, 1.0/26624.0);
    // layer 6
    convblock<64,13,64,64,3,1,1,13,2,2,6>
        <<<dim3(NBATCH,1), 256, 57344, stream>>>(bufA, W[5], wsc + 180, abbuf + 232, bufB, stats + 360);
    bnparam_kernel<<<1,128,0,stream>>>(stats + 360, Gp[5], Bp[5], abbuf + 360, 64, 1.0/12288.0);
    // layer 7
    convblock<64,6,72,72,3,1,1,6,2,2,3>
        <<<dim3(NBATCH,1), 256, 59424, stream>>>(bufB, W[6], wsc + 244, abbuf + 360, bufA, stats + 488);
    bnparam_kernel<<<1,128,0,stream>>>(stats + 488, Gp[6], Bp[6], abbuf + 488, 72, 1.0/6144.0);
    // FC
    fc_kernel<<<NBATCH, 256, 0, stream>>>(bufA, abbuf + 488, WFC, wsc + 316, outp);
}

// Round 2
// 729.311 us; speedup vs baseline: 2.8558x; 2.8558x over previous
//
#include <hip/hip_runtime.h>
#include <math.h>
#include <stdint.h>

#define NBATCH 2048

__device__ __forceinline__ float signf(float v) {
    return (v > 0.f) ? 1.f : ((v < 0.f) ? -1.f : 0.f);
}

// ---------------- weight scales: all 8 layers in one kernel ------------------
struct ScaleArgs {
    const float* w[8];
    int cum[9];   // output-channel offsets {0,8,20,52,116,180,244,316,321}
    int per[8];   // elements per output channel
};

__global__ void wscale_all(ScaleArgs sa, float* __restrict__ wsc) {
    int o = blockIdx.x;
    int L = 0;
    while (L < 7 && o >= sa.cum[L + 1]) ++L;
    int oo = o - sa.cum[L];
    int per = sa.per[L];
    const float* wo = sa.w[L] + (size_t)oo * per;
    float s = 0.f;
    for (int i = threadIdx.x; i < per; i += 64) s += fabsf(wo[i]);
    #pragma unroll
    for (int off = 32; off > 0; off >>= 1) s += __shfl_down(s, off);
    if (threadIdx.x == 0) wsc[o] = s / (float)per;
}

// ---------------- pack weight signs into bitmasks (layers 2..7) --------------
struct PackArgs {
    const float* w[6];
    int cum[7];    // entry (o*K) offsets {0,144,432,880,1200,1392,1608}
    int CIN[6];
    int K[6];
    int WPP[6];
    int woff[6];   // word offsets in wm buffer {0,144,432,880,1520,1904}
};

__global__ void wpack_all(PackArgs pa, uint32_t* __restrict__ wm) {
    int gid = blockIdx.x * 64 + threadIdx.x;
    if (gid >= pa.cum[6]) return;
    int L = 0;
    while (L < 5 && gid >= pa.cum[L + 1]) ++L;
    int idx = gid - pa.cum[L];
    int K = pa.K[L], CIN = pa.CIN[L], WPP = pa.WPP[L];
    int o = idx / K, k = idx % K;
    const float* w = pa.w[L];
    uint32_t m0 = 0, m1 = 0;
    for (int c = 0; c < CIN; ++c) {
        float v = w[((size_t)o * CIN + c) * K + k];
        uint32_t bit = (v < 0.f) ? 1u : 0u;
        if (c < 32) m0 |= bit << c; else m1 |= bit << (c - 32);
    }
    uint32_t* dst = wm + pa.woff[L] + (size_t)idx * WPP;
    dst[0] = m0;
    if (WPP == 2) dst[1] = m1;
}

// ---------------- BN fold: stats -> affine (a,b) ----------------------------
__global__ void bnparam_kernel(const double* __restrict__ stats,
                               const float* __restrict__ gamma,
                               const float* __restrict__ beta,
                               float* __restrict__ ab, int O, double cntInv) {
    int o = threadIdx.x;
    if (o < O) {
        double mean = stats[o] * cntInv;
        double var  = stats[O + o] * cntInv - mean * mean;
        double inv  = 1.0 / sqrt(var + 1e-5);
        double a    = (double)gamma[o] * inv;
        ab[o]     = (float)a;
        ab[O + o] = (float)((double)beta[o] - mean * a);
    }
}

// ---------------- layer 1: fp32 input, K=16, stride 2 -----------------------
// Even/odd split: out[p] = sum_m A[p+m]*w[2m] + B[p+m]*w[2m+1],
// A[j]=X(2j-7), B[j]=X(2j-6). Lane computes 8 consecutive p from aligned
// float4 window loads; full register reuse of the 16-float windows.
__global__ __launch_bounds__(256) void convblock1(
    const float* __restrict__ x, const float* __restrict__ w,
    const float* __restrict__ wsc, float* __restrict__ out,
    double* __restrict__ stats)
{
    __shared__ float AB[2][1808];
    __shared__ float cvxs[7200];   // phase 1: xs[3600]; phase 2: cv[4*1800]
    __shared__ float wgs[64];
    const int n = blockIdx.x, o0 = blockIdx.y * 4, tid = threadIdx.x;

    float* xs = cvxs;
    const float* xn = x + (size_t)n * 3600;
    for (int i = tid; i < 3600; i += 256) xs[i] = xn[i];
    if (tid < 64) wgs[tid] = signf(w[o0 * 16 + tid]);  // [c][k], c=tid>>4
    __syncthreads();

    for (int j = tid; j < 1808; j += 256) {
        int ta = 2 * j - 7, tb = 2 * j - 6;
        AB[0][j] = (ta >= 0 && ta < 3600) ? xs[ta] : 0.f;
        AB[1][j] = (tb >= 0 && tb < 3600) ? xs[tb] : 0.f;
    }
    __syncthreads();

    float* cv = cvxs;  // xs dead from here
    const int ch = tid >> 6, lane = tid & 63;
    float wr[16];
    #pragma unroll
    for (int k = 0; k < 16; ++k) wr[k] = wgs[ch * 16 + k];

    for (int run = lane; run < 225; run += 64) {
        int p0 = run * 8;
        float4 a0 = *(const float4*)&AB[0][p0];
        float4 a1 = *(const float4*)&AB[0][p0 + 4];
        float4 a2 = *(const float4*)&AB[0][p0 + 8];
        float4 a3 = *(const float4*)&AB[0][p0 + 12];
        float4 b0 = *(const float4*)&AB[1][p0];
        float4 b1 = *(const float4*)&AB[1][p0 + 4];
        float4 b2 = *(const float4*)&AB[1][p0 + 8];
        float4 b3 = *(const float4*)&AB[1][p0 + 12];
        float A[16] = {a0.x,a0.y,a0.z,a0.w, a1.x,a1.y,a1.z,a1.w,
                       a2.x,a2.y,a2.z,a2.w, a3.x,a3.y,a3.z,a3.w};
        float B[16] = {b0.x,b0.y,b0.z,b0.w, b1.x,b1.y,b1.z,b1.w,
                       b2.x,b2.y,b2.z,b2.w, b3.x,b3.y,b3.z,b3.w};
        float acc[8];
        #pragma unroll
        for (int p = 0; p < 8; ++p) acc[p] = 0.f;
        #pragma unroll
        for (int m = 0; m < 8; ++m) {
            #pragma unroll
            for (int p = 0; p < 8; ++p) {
                acc[p] = fmaf(A[p + m], wr[2 * m], acc[p]);
                acc[p] = fmaf(B[p + m], wr[2 * m + 1], acc[p]);
            }
        }
        #pragma unroll
        for (int p = 0; p < 8; ++p) cv[ch * 1800 + p0 + p] = acc[p];
    }
    __syncthreads();

    // pool (k=8, s=4) + scale + write + per-channel stats (one wave per ch)
    float scale = wsc[o0 + ch];
    float* on = out + ((size_t)n * 8 + o0 + ch) * 449;
    double s = 0.0, s2 = 0.0;
    for (int lp = lane; lp < 449; lp += 64) {
        const float* c0 = cv + ch * 1800 + lp * 4;
        float m = c0[0];
        #pragma unroll
        for (int j = 1; j < 8; ++j) m = fmaxf(m, c0[j]);
        m *= scale;
        on[lp] = m;
        s += m; s2 += (double)m * (double)m;
    }
    #pragma unroll
    for (int off = 32; off > 0; off >>= 1) {
        s  += __shfl_down(s,  off);
        s2 += __shfl_down(s2, off);
    }
    if (lane == 0) {
        atomicAdd(&stats[o0 + ch], s);
        atomicAdd(&stats[8 + o0 + ch], s2);
    }
}

// ---------------- layers 2..7: binary conv via XOR+popcount -----------------
template <int CIN, int LIN, int O, int K, int STRIDE, int PAD,
          int LCONV, int PK, int PS, int LP, int WPP>
__global__ __launch_bounds__(256) void convblock_bin(
    const float* __restrict__ xprev, const uint32_t* __restrict__ wm,
    const float* __restrict__ wsc, const float* __restrict__ ab,
    float* __restrict__ out, double* __restrict__ stats)
{
    extern __shared__ uint32_t ldsu[];
    uint32_t* xm  = ldsu;                       // LIN*WPP words
    uint32_t* wml = xm + LIN * WPP;             // O*K*WPP words
    int*      cvi = (int*)(wml + O * K * WPP);  // O*LCONV ints
    float*    pl  = (float*)(cvi + O * LCONV);  // O*LP floats

    const int n = blockIdx.x, tid = threadIdx.x;
    const float* xn = xprev + (size_t)n * CIN * LIN;

    // pack prev activations: bit c = 1 iff sign(a*x+b) == -1
    for (int pos = tid; pos < LIN; pos += 256) {
        uint32_t m0 = 0, m1 = 0;
        #pragma unroll
        for (int c = 0; c < CIN; ++c) {
            float v = fmaf(ab[c], xn[(size_t)c * LIN + pos], ab[CIN + c]);
            uint32_t bit = (v < 0.f) ? 1u : 0u;
            if (c < 32) m0 |= bit << c; else m1 |= bit << (c - 32);
        }
        xm[pos * WPP] = m0;
        if constexpr (WPP == 2) xm[pos * WPP + 1] = m1;
    }
    for (int i = tid; i < O * K * WPP; i += 256) wml[i] = wm[i];
    __syncthreads();

    // conv: dot = CIN*valid_taps - 2*popcount(x ^ w)
    constexpr int CV = O * LCONV;
    for (int idx = tid; idx < CV; idx += 256) {
        int oo = idx / LCONV, lc = idx - oo * LCONV;
        int base = lc * STRIDE - PAD;
        const uint32_t* wo = wml + oo * K * WPP;
        int dot;
        if (base >= 0 && base + K <= LIN) {
            int p = 0;
            #pragma unroll
            for (int k = 0; k < K; ++k) {
                if constexpr (WPP == 1) {
                    p += __popc(xm[base + k] ^ wo[k]);
                } else {
                    uint64_t xv = *(const uint64_t*)(xm + (size_t)(base + k) * 2);
                    uint64_t wv = *(const uint64_t*)(wo + (size_t)k * 2);
                    p += __popcll(xv ^ wv);
                }
            }
            dot = CIN * K - 2 * p;
        } else {
            int p = 0, nv = 0;
            #pragma unroll
            for (int k = 0; k < K; ++k) {
                int q = base + k;
                if (q >= 0 && q < LIN) {
                    ++nv;
                    if constexpr (WPP == 1) {
                        p += __popc(xm[q] ^ wo[k]);
                    } else {
                        uint64_t xv = *(const uint64_t*)(xm + (size_t)q * 2);
                        uint64_t wv = *(const uint64_t*)(wo + (size_t)k * 2);
                        p += __popcll(xv ^ wv);
                    }
                }
            }
            dot = CIN * nv - 2 * p;
        }
        cvi[idx] = dot;
    }
    __syncthreads();

    // pool + scale + write
    float* on = out + (size_t)n * O * LP;
    for (int idx = tid; idx < O * LP; idx += 256) {
        int oo = idx / LP, lp = idx - oo * LP;
        const int* c0 = cvi + oo * LCONV + lp * PS;
        int m = c0[0];
        #pragma unroll
        for (int j = 1; j < PK; ++j) m = max(m, c0[j]);
        float mv = (float)m * wsc[oo];
        pl[idx] = mv;
        on[idx] = mv;
    }
    __syncthreads();

    if (tid < O) {
        double s = 0.0, s2 = 0.0;
        const float* po = pl + tid * LP;
        for (int l = 0; l < LP; ++l) { double v = po[l]; s += v; s2 += v * v; }
        atomicAdd(&stats[tid], s);
        atomicAdd(&stats[O + tid], s2);
    }
}

// ---------------- FC over flattened [72*3] ----------------------------------
__global__ __launch_bounds__(256) void fc_kernel(
    const float* __restrict__ p7, const float* __restrict__ ab,
    const float* __restrict__ wfc, const float* __restrict__ wsc,
    float* __restrict__ out)
{
    __shared__ float act[216];
    int n = blockIdx.x, tid = threadIdx.x;
    for (int i = tid; i < 216; i += 256) {
        int c = i / 3;
        act[i] = signf(fmaf(ab[c], p7[(size_t)n * 216 + i], ab[72 + c]));
    }
    __syncthreads();
    if (tid < 5) {
        const float* wr = wfc + tid * 216;
        float s = 0.f;
        #pragma unroll 8
        for (int i = 0; i < 216; ++i) s += act[i] * signf(wr[i]);
        out[(size_t)n * 5 + tid] = s * wsc[tid];
    }
}

extern "C" void kernel_launch(void* const* d_in, const int* in_sizes, int n_in,
                              void* d_out, int out_size, void* d_ws, size_t ws_size,
                              hipStream_t stream) {
    const float* x = (const float*)d_in[0];
    const float* W[7]; const float* Gp[7]; const float* Bp[7];
    for (int i = 0; i < 7; ++i) {
        W[i]  = (const float*)d_in[1 + 3 * i];
        Gp[i] = (const float*)d_in[2 + 3 * i];
        Bp[i] = (const float*)d_in[3 + 3 * i];
    }
    const float* WFC = (const float*)d_in[22];
    float* outp = (float*)d_out;

    // workspace layout (identical footprint to R1 + wm scratch living in d_out,
    // which is dead until fc_kernel writes it last)
    char* ws = (char*)d_ws;
    double* stats = (double*)ws;                    // 632 doubles
    float*  abbuf = (float*)(ws + 5120);            // 632 floats
    float*  wsc   = (float*)(ws + 7680);            // 321 floats
    float*  bufA  = (float*)(ws + 9216);            // 7,356,416 floats
    float*  bufB  = bufA + 7356416;                 // 3,407,872 floats
    uint32_t* wmb = (uint32_t*)d_out;               // 2336 words (9344 B < 40 KB)

    hipMemsetAsync(stats, 0, 632 * sizeof(double), stream);

    ScaleArgs sa;
    { const float* wsrc[8] = {W[0],W[1],W[2],W[3],W[4],W[5],W[6],WFC};
      int cum[9] = {0,8,20,52,116,180,244,316,321};
      int per[8] = {16,96,108,224,320,192,192,216};
      for (int i=0;i<8;++i){ sa.w[i]=wsrc[i]; sa.per[i]=per[i]; }
      for (int i=0;i<9;++i) sa.cum[i]=cum[i]; }
    wscale_all<<<321, 64, 0, stream>>>(sa, wsc);

    PackArgs pa;
    { const float* wsrc[6] = {W[1],W[2],W[3],W[4],W[5],W[6]};
      int cum[7]  = {0,144,432,880,1200,1392,1608};
      int cin[6]  = {8,12,32,64,64,64};
      int kk[6]   = {12,9,7,5,3,3};
      int wpp[6]  = {1,1,1,2,2,2};
      int woff[6] = {0,144,432,880,1520,1904};
      for (int i=0;i<6;++i){ pa.w[i]=wsrc[i]; pa.CIN[i]=cin[i]; pa.K[i]=kk[i];
                             pa.WPP[i]=wpp[i]; pa.woff[i]=woff[i]; }
      for (int i=0;i<7;++i) pa.cum[i]=cum[i]; }
    wpack_all<<<(1608 + 63) / 64, 64, 0, stream>>>(pa, wmb);

    // layer 1
    convblock1<<<dim3(NBATCH, 2), 256, 0, stream>>>(x, W[0], wsc + 0, bufA, stats + 0);
    bnparam_kernel<<<1, 128, 0, stream>>>(stats + 0, Gp[0], Bp[0], abbuf + 0, 8, 1.0 / 919552.0);
    // layer 2
    convblock_bin<8,449,12,12,2,5,224,4,2,111,1>
        <<<NBATCH, 256, 18452, stream>>>(bufA, wmb + 0, wsc + 8, abbuf + 0, bufB, stats + 16);
    bnparam_kernel<<<1, 128, 0, stream>>>(stats + 16, Gp[1], Bp[1], abbuf + 16, 12, 1.0 / 227328.0);
    // layer 3
    convblock_bin<12,111,32,9,1,4,111,5,2,54,1>
        <<<NBATCH, 256, 22716, stream>>>(bufB, wmb + 144, wsc + 20, abbuf + 16, bufA, stats + 40);
    bnparam_kernel<<<1, 128, 0, stream>>>(stats + 40, Gp[2], Bp[2], abbuf + 40, 32, 1.0 / 110592.0);
    // layer 4
    convblock_bin<32,54,64,7,1,3,54,4,2,26,1>
        <<<NBATCH, 256, 22488, stream>>>(bufA, wmb + 432, wsc + 52, abbuf + 40, bufB, stats + 104);
    bnparam_kernel<<<1, 128, 0, stream>>>(stats + 104, Gp[3], Bp[3], abbuf + 104, 64, 1.0 / 53248.0);
    // layer 5
    convblock_bin<64,26,64,5,1,2,26,2,2,13,2>
        <<<NBATCH, 256, 12752, stream>>>(bufB, wmb + 880, wsc + 116, abbuf + 104, bufA, stats + 232);
    bnparam_kernel<<<1, 128, 0, stream>>>(stats + 232, Gp[4], Bp[4], abbuf + 232, 64, 1.0 / 26624.0);
    // layer 6
    convblock_bin<64,13,64,3,1,1,13,2,2,6,2>
        <<<NBATCH, 256, 6504, stream>>>(bufA, wmb + 1520, wsc + 180, abbuf + 232, bufB, stats + 360);
    bnparam_kernel<<<1, 128, 0, stream>>>(stats + 360, Gp[5], Bp[5], abbuf + 360, 64, 1.0 / 12288.0);
    // layer 7
    convblock_bin<64,6,72,3,1,1,6,2,2,3,2>
        <<<NBATCH, 256, 4368, stream>>>(bufB, wmb + 1904, wsc + 244, abbuf + 360, bufA, stats + 488);
    bnparam_kernel<<<1, 128, 0, stream>>>(stats + 488, Gp[6], Bp[6], abbuf + 488, 72, 1.0 / 6144.0);
    // FC (overwrites d_out; wm scratch dead by now)
    fc_kernel<<<NBATCH, 256, 0, stream>>>(bufA, abbuf + 488, WFC, wsc + 316, outp);
}

// Round 3
// 315.696 us; speedup vs baseline: 6.5974x; 2.3102x over previous
//
#include <hip/hip_runtime.h>
#include <math.h>
#include <stdint.h>

#define NBATCH 2048
#define NSLOT 32

__device__ __forceinline__ float signf(float v) {
    return (v > 0.f) ? 1.f : ((v < 0.f) ? -1.f : 0.f);
}

// ---------------- weight scales: all 8 layers in one kernel ------------------
struct ScaleArgs {
    const float* w[8];
    int cum[9];
    int per[8];
};

__global__ void wscale_all(ScaleArgs sa, float* __restrict__ wsc) {
    int o = blockIdx.x;
    int L = 0;
    while (L < 7 && o >= sa.cum[L + 1]) ++L;
    int oo = o - sa.cum[L];
    int per = sa.per[L];
    const float* wo = sa.w[L] + (size_t)oo * per;
    float s = 0.f;
    for (int i = threadIdx.x; i < per; i += 64) s += fabsf(wo[i]);
    #pragma unroll
    for (int off = 32; off > 0; off >>= 1) s += __shfl_down(s, off);
    if (threadIdx.x == 0) wsc[o] = s / (float)per;
}

// ---------------- pack weight signs into bitmasks (layers 2..7) --------------
struct PackArgs {
    const float* w[6];
    int cum[7];
    int CIN[6];
    int K[6];
    int WPP[6];
    int woff[6];
};

__global__ void wpack_all(PackArgs pa, uint32_t* __restrict__ wm) {
    int gid = blockIdx.x * 64 + threadIdx.x;
    if (gid >= pa.cum[6]) return;
    int L = 0;
    while (L < 5 && gid >= pa.cum[L + 1]) ++L;
    int idx = gid - pa.cum[L];
    int K = pa.K[L], CIN = pa.CIN[L], WPP = pa.WPP[L];
    int o = idx / K, k = idx % K;
    const float* w = pa.w[L];
    uint32_t m0 = 0, m1 = 0;
    for (int c = 0; c < CIN; ++c) {
        float v = w[((size_t)o * CIN + c) * K + k];
        uint32_t bit = (v < 0.f) ? 1u : 0u;
        if (c < 32) m0 |= bit << c; else m1 |= bit << (c - 32);
    }
    uint32_t* dst = wm + pa.woff[L] + (size_t)idx * WPP;
    dst[0] = m0;
    if (WPP == 2) dst[1] = m1;
}

// ---------------- layer 1: register-resident conv, K=16, stride 2 -----------
// Lane r computes conv positions p=8r..8r+11 for all 8 channels from a 40-float
// window loaded straight from global (taps are consecutive: x[2p-7+k]).
// Pools in-register (pk=8, ps=4 -> lp=2r from acc[0..7], lp=2r+1 from acc[4..11]).
// Output transposed: out[n][449][8].
__global__ __launch_bounds__(256) void convblock1(
    const float* __restrict__ x, const float* __restrict__ w,
    const float* __restrict__ wsc, float* __restrict__ out,
    double* __restrict__ stats)
{
    __shared__ float wgs[128];
    __shared__ double sred[16];
    const int n = blockIdx.x, tid = threadIdx.x, l = tid & 63;
    if (tid < 128) wgs[tid] = signf(w[tid]);
    if (tid < 16) sred[tid] = 0.0;
    __syncthreads();

    const int r = tid;  // run id 0..224
    const float* xn = x + (size_t)n * 3600;
    float m0[8], m1[8];
    #pragma unroll
    for (int ch = 0; ch < 8; ++ch) { m0[ch] = 0.f; m1[ch] = 0.f; }

    if (r < 225) {
        float f[40];  // f[i] = x[16r-8+i]; taps: f[2j+1+k]
        const int g0 = 16 * r - 8;
        #pragma unroll
        for (int b = 0; b < 10; ++b) {
            const int g = g0 + 4 * b;
            if (g >= 0 && g <= 3596) {
                const float4 v = *(const float4*)(xn + g);
                f[4*b] = v.x; f[4*b+1] = v.y; f[4*b+2] = v.z; f[4*b+3] = v.w;
            } else {
                f[4*b] = 0.f; f[4*b+1] = 0.f; f[4*b+2] = 0.f; f[4*b+3] = 0.f;
            }
        }
        #pragma unroll
        for (int ch = 0; ch < 8; ++ch) {
            float acc[12];
            #pragma unroll
            for (int j = 0; j < 12; ++j) acc[j] = 0.f;
            #pragma unroll
            for (int k = 0; k < 16; ++k) {
                const float wk = wgs[ch * 16 + k];
                #pragma unroll
                for (int j = 0; j < 12; ++j)
                    acc[j] = fmaf(f[2*j + 1 + k], wk, acc[j]);
            }
            const float lo  = fmaxf(fmaxf(acc[0], acc[1]), fmaxf(acc[2], acc[3]));
            const float mid = fmaxf(fmaxf(acc[4], acc[5]), fmaxf(acc[6], acc[7]));
            const float hi  = fmaxf(fmaxf(acc[8], acc[9]), fmaxf(acc[10], acc[11]));
            const float sc = wsc[ch];
            m0[ch] = fmaxf(lo, mid) * sc;
            m1[ch] = (r < 224) ? fmaxf(mid, hi) * sc : 0.f;
        }
        float* on = out + ((size_t)n * 449 + 2 * r) * 8;
        *(float4*)(on + 0) = make_float4(m0[0], m0[1], m0[2], m0[3]);
        *(float4*)(on + 4) = make_float4(m0[4], m0[5], m0[6], m0[7]);
        if (r < 224) {
            *(float4*)(on + 8)  = make_float4(m1[0], m1[1], m1[2], m1[3]);
            *(float4*)(on + 12) = make_float4(m1[4], m1[5], m1[6], m1[7]);
        }
    }

    #pragma unroll
    for (int ch = 0; ch < 8; ++ch) {
        double s  = (double)m0[ch] + (double)m1[ch];
        double s2 = (double)m0[ch] * m0[ch] + (double)m1[ch] * m1[ch];
        #pragma unroll
        for (int off = 32; off; off >>= 1) {
            s  += __shfl_down(s, off);
            s2 += __shfl_down(s2, off);
        }
        if (l == 0) {
            atomicAdd(&sred[ch], s);
            atomicAdd(&sred[8 + ch], s2);
        }
    }
    __syncthreads();
    if (tid < 16) {
        double* so = stats + (size_t)(blockIdx.x & (NSLOT - 1)) * 16;
        atomicAdd(&so[tid], sred[tid]);
    }
}

// ---------------- layers 2..7: ballot-pack + XOR/popcount conv --------------
// Input transposed [n][LIN][CIN] (pre-BN floats); BN affine computed in-block
// from slotted double stats of the previous layer. Output [n][LP][O].
template <int CIN, int LIN, int O, int K, int STRIDE, int PAD,
          int LCONV, int LCONVP, int PK, int PS, int LP, int WPP>
__global__ __launch_bounds__(256) void convblock_bin(
    const float* __restrict__ xprev, const uint32_t* __restrict__ wm,
    const float* __restrict__ wsc,
    const double* __restrict__ stats_in, const float* __restrict__ gamma,
    const float* __restrict__ beta, const double cntInv,
    float* __restrict__ out, double* __restrict__ stats_out)
{
    extern __shared__ uint32_t ldsu[];
    uint32_t* xm  = ldsu;                        // LIN*WPP words (8B-aligned)
    uint32_t* wml = xm + LIN * WPP;              // O*K*WPP words
    int*      cvi = (int*)(wml + O * K * WPP);   // O*LCONVP ints (odd stride)
    float*    pl  = (float*)(cvi + O * LCONVP);  // LP*O floats
    __shared__ float abA[CIN], abB[CIN];

    const int n = blockIdx.x, tid = threadIdx.x;
    const int wv = tid >> 6, l = tid & 63;
    const float* xn = xprev + (size_t)n * LIN * CIN;

    if (tid < CIN) {
        double s = 0.0, s2 = 0.0;
        #pragma unroll
        for (int sl = 0; sl < NSLOT; ++sl) {
            s  += stats_in[sl * 2 * CIN + tid];
            s2 += stats_in[sl * 2 * CIN + CIN + tid];
        }
        const double mean = s * cntInv;
        const double var  = s2 * cntInv - mean * mean;
        const double inv  = 1.0 / sqrt(var + 1e-5);
        const double a    = (double)gamma[tid] * inv;
        abA[tid] = (float)a;
        abB[tid] = (float)((double)beta[tid] - mean * a);
    }
    for (int i = tid; i < O * K * WPP; i += 256) wml[i] = wm[i];
    __syncthreads();

    // pack: lane=channel, ballot -> bitmask(s) for PPW positions per wave
    constexpr int PPW = 64 / CIN;
    const int pw = l / CIN, c = l - pw * CIN;
    for (int pb = wv * PPW; pb < LIN; pb += 4 * PPW) {
        const int pos = pb + pw;
        const bool act = (pw < PPW) && (pos < LIN);
        float v = 0.f;
        if (act) v = fmaf(abA[c], xn[(size_t)pb * CIN + l], abB[c]);
        const unsigned long long bal = __ballot(act && (v < 0.f));
        if (act && c == 0) {
            if constexpr (WPP == 2) {
                ((uint64_t*)xm)[pos] = (uint64_t)bal;
            } else if constexpr (CIN == 32) {
                xm[pos] = (uint32_t)(bal >> (pw * 32));
            } else {
                xm[pos] = (uint32_t)((bal >> (pw * CIN)) & ((1ull << CIN) - 1));
            }
        }
    }
    __syncthreads();

    // conv: dot = CIN*valid_taps - 2*popcount(x ^ w)
    constexpr int CV = O * LCONV;
    for (int idx = tid; idx < CV; idx += 256) {
        const int oo = idx / LCONV, lc = idx - oo * LCONV;
        const int base = lc * STRIDE - PAD;
        int dot;
        if constexpr (WPP == 2) {
            const uint64_t* xm64 = (const uint64_t*)xm;
            const uint64_t* wo = (const uint64_t*)wml + (size_t)oo * K;
            if (base >= 0 && base + K <= LIN) {
                int p = 0;
                #pragma unroll
                for (int k = 0; k < K; ++k) p += __popcll(xm64[base + k] ^ wo[k]);
                dot = CIN * K - 2 * p;
            } else {
                int p = 0, nv = 0;
                #pragma unroll
                for (int k = 0; k < K; ++k) {
                    const int q = base + k;
                    if (q >= 0 && q < LIN) { ++nv; p += __popcll(xm64[q] ^ wo[k]); }
                }
                dot = CIN * nv - 2 * p;
            }
        } else {
            const uint32_t* wo = wml + (size_t)oo * K;
            if (base >= 0 && base + K <= LIN) {
                int p = 0;
                #pragma unroll
                for (int k = 0; k < K; ++k) p += __popc(xm[base + k] ^ wo[k]);
                dot = CIN * K - 2 * p;
            } else {
                int p = 0, nv = 0;
                #pragma unroll
                for (int k = 0; k < K; ++k) {
                    const int q = base + k;
                    if (q >= 0 && q < LIN) { ++nv; p += __popc(xm[q] ^ wo[k]); }
                }
                dot = CIN * nv - 2 * p;
            }
        }
        cvi[oo * LCONVP + lc] = dot;
    }
    __syncthreads();

    // pool + scale + write transposed [lp][O] (coalesced)
    float* on = out + (size_t)n * LP * O;
    for (int idx = tid; idx < LP * O; idx += 256) {
        const int lp = idx / O, oo = idx - lp * O;
        const int* c0 = cvi + oo * LCONVP + lp * PS;
        int m = c0[0];
        #pragma unroll
        for (int j = 1; j < PK; ++j) m = max(m, c0[j]);
        const float mv = (float)m * wsc[oo];
        pl[idx] = mv;
        on[idx] = mv;
    }
    __syncthreads();

    if (tid < O) {
        double s = 0.0, s2 = 0.0;
        for (int lp = 0; lp < LP; ++lp) {
            const double v = pl[lp * O + tid];
            s += v; s2 += v * v;
        }
        double* so = stats_out + (size_t)(n & (NSLOT - 1)) * 2 * O;
        atomicAdd(&so[tid], s);
        atomicAdd(&so[O + tid], s2);
    }
}

// ---------------- FC over flattened [72*3] (computes L7 BN inline) ----------
__global__ __launch_bounds__(128) void fc_kernel(
    const float* __restrict__ p7, const double* __restrict__ stats_in,
    const float* __restrict__ gamma, const float* __restrict__ beta,
    const float* __restrict__ wfc, const float* __restrict__ wsc,
    float* __restrict__ out)
{
    __shared__ float abA[72], abB[72], act[216];
    const int n = blockIdx.x, tid = threadIdx.x;
    if (tid < 72) {
        double s = 0.0, s2 = 0.0;
        #pragma unroll
        for (int sl = 0; sl < NSLOT; ++sl) {
            s  += stats_in[sl * 144 + tid];
            s2 += stats_in[sl * 144 + 72 + tid];
        }
        const double mean = s / 6144.0;
        const double var  = s2 / 6144.0 - mean * mean;
        const double inv  = 1.0 / sqrt(var + 1e-5);
        const double a    = (double)gamma[tid] * inv;
        abA[tid] = (float)a;
        abB[tid] = (float)((double)beta[tid] - mean * a);
    }
    __syncthreads();
    for (int i = tid; i < 216; i += 128) {
        const int c = i / 3, lp = i - c * 3;   // reference flattens [72,3]
        act[i] = signf(fmaf(abA[c], p7[(size_t)n * 216 + lp * 72 + c], abB[c]));
    }
    __syncthreads();
    if (tid < 5) {
        const float* wr = wfc + tid * 216;
        float s = 0.f;
        #pragma unroll 8
        for (int i = 0; i < 216; ++i) s += act[i] * signf(wr[i]);
        out[(size_t)n * 5 + tid] = s * wsc[tid];
    }
}

extern "C" void kernel_launch(void* const* d_in, const int* in_sizes, int n_in,
                              void* d_out, int out_size, void* d_ws, size_t ws_size,
                              hipStream_t stream) {
    const float* x = (const float*)d_in[0];
    const float* W[7]; const float* Gp[7]; const float* Bp[7];
    for (int i = 0; i < 7; ++i) {
        W[i]  = (const float*)d_in[1 + 3 * i];
        Gp[i] = (const float*)d_in[2 + 3 * i];
        Bp[i] = (const float*)d_in[3 + 3 * i];
    }
    const float* WFC = (const float*)d_in[22];
    float* outp = (float*)d_out;

    // workspace layout
    char* ws = (char*)d_ws;
    float*  bufA  = (float*)ws;                          // 7,356,416 floats
    float*  bufB  = (float*)(ws + 29425664);             // 3,407,872 floats
    double* stats = (double*)(ws + 43057152);            // 32 slots x 632 doubles
    float*  wsc   = (float*)(ws + 43218944);             // 321 floats
    uint32_t* wmb = (uint32_t*)d_out;                    // 2336 words, dead before fc

    hipMemsetAsync(stats, 0, (size_t)NSLOT * 632 * sizeof(double), stream);

    ScaleArgs sa;
    { const float* wsrc[8] = {W[0],W[1],W[2],W[3],W[4],W[5],W[6],WFC};
      int cum[9] = {0,8,20,52,116,180,244,316,321};
      int per[8] = {16,96,108,224,320,192,192,216};
      for (int i=0;i<8;++i){ sa.w[i]=wsrc[i]; sa.per[i]=per[i]; }
      for (int i=0;i<9;++i) sa.cum[i]=cum[i]; }
    wscale_all<<<321, 64, 0, stream>>>(sa, wsc);

    PackArgs pa;
    { const float* wsrc[6] = {W[1],W[2],W[3],W[4],W[5],W[6]};
      int cum[7]  = {0,144,432,880,1200,1392,1608};
      int cin[6]  = {8,12,32,64,64,64};
      int kk[6]   = {12,9,7,5,3,3};
      int wpp[6]  = {1,1,1,2,2,2};
      int woff[6] = {0,144,432,880,1520,1904};
      for (int i=0;i<6;++i){ pa.w[i]=wsrc[i]; pa.CIN[i]=cin[i]; pa.K[i]=kk[i];
                             pa.WPP[i]=wpp[i]; pa.woff[i]=woff[i]; }
      for (int i=0;i<7;++i) pa.cum[i]=cum[i]; }
    wpack_all<<<(1608 + 63) / 64, 64, 0, stream>>>(pa, wmb);

    // stats slot offsets (doubles): L1 0, L2 512, L3 1280, L4 3328, L5 7424,
    // L6 11520, L7 15616
    convblock1<<<NBATCH, 256, 0, stream>>>(x, W[0], wsc + 0, bufA, stats + 0);

    convblock_bin<8,449,12,12,2,5,224,225,4,2,111,1>
        <<<NBATCH, 256, 18500, stream>>>(bufA, wmb + 0, wsc + 8,
            stats + 0, Gp[0], Bp[0], 1.0/919552.0, bufB, stats + 512);

    convblock_bin<12,111,32,9,1,4,111,111,5,2,54,1>
        <<<NBATCH, 256, 22716, stream>>>(bufB, wmb + 144, wsc + 20,
            stats + 512, Gp[1], Bp[1], 1.0/227328.0, bufA, stats + 1280);

    convblock_bin<32,54,64,7,1,3,54,55,4,2,26,1>
        <<<NBATCH, 256, 22744, stream>>>(bufA, wmb + 432, wsc + 52,
            stats + 1280, Gp[2], Bp[2], 1.0/110592.0, bufB, stats + 3328);

    convblock_bin<64,26,64,5,1,2,26,27,2,2,13,2>
        <<<NBATCH, 256, 13008, stream>>>(bufB, wmb + 880, wsc + 116,
            stats + 3328, Gp[3], Bp[3], 1.0/53248.0, bufA, stats + 7424);

    convblock_bin<64,13,64,3,1,1,13,13,2,2,6,2>
        <<<NBATCH, 256, 6504, stream>>>(bufA, wmb + 1520, wsc + 180,
            stats + 7424, Gp[4], Bp[4], 1.0/26624.0, bufB, stats + 11520);

    convblock_bin<64,6,72,3,1,1,6,7,2,2,3,2>
        <<<NBATCH, 256, 4656, stream>>>(bufB, wmb + 1904, wsc + 244,
            stats + 11520, Gp[5], Bp[5], 1.0/12288.0, bufA, stats + 15616);

    fc_kernel<<<NBATCH, 128, 0, stream>>>(bufA, stats + 15616, Gp[6], Bp[6],
                                          WFC, wsc + 316, outp);
}